// Round 4
// baseline (76.604 us; speedup 1.0000x reference)
//
#include <hip/hip_runtime.h>
#include <hip/hip_bf16.h>

#define B_  512
#define T_  256
#define C_  384
#define H_  64
#define SCALE_ 0.05103103630798287f   // 384^-0.5

typedef float f32x4  __attribute__((ext_vector_type(4)));
typedef short bf16x8 __attribute__((ext_vector_type(8)));
typedef short bf16x4 __attribute__((ext_vector_type(4)));

__device__ __forceinline__ unsigned short f2bf(float f) {
    union { float f; unsigned u; } v; v.f = f;
    unsigned r = v.u + 0x7FFFu + ((v.u >> 16) & 1u);   // RNE
    return (unsigned short)(r >> 16);
}

__device__ __forceinline__ unsigned cvt_pk_bf16(float lo, float hi) {
    unsigned r;
    asm("v_cvt_pk_bf16_f32 %0, %1, %2" : "=v"(r) : "v"(lo), "v"(hi));
    return r;
}

// Element index into an XOR-swizzled [R][64]-short tile (row = 128 B = 8 x 16B blocks).
__device__ __forceinline__ int swz64(int row, int col) {
    return row * 64 + (((col >> 3) ^ (row & 7)) << 3) + (col & 7);
}

// LDS layout (shorts), total 67584 shorts = 135168 B:
//  [0,     24576)  wst[2][192*64]  W^T double buffer   | alias after phase1: Qs[256][64] swz
//  [24576, 34816)  Pb: 16 waves x [16][40] swizzled P scratch
//  [34816, 51200)  Ks[256][64] swz
//  [51200, 67584)  Vt[64][256] swz (h-major, t contiguous)
//
// Phase 1 wave grid: 8 row-bands (32 rows, 2 MFMA strips) x 2 col-halves (96 cols, 6 frags).
// Each W^T fragment read by 8 waves (was 16) and feeds 2 MFMAs (was 1).
__global__ __launch_bounds__(1024, 4) void att_head_kernel(
    const float* __restrict__ x,  const float* __restrict__ Wk,
    const float* __restrict__ Wq, const float* __restrict__ Wv,
    float* __restrict__ out)
{
    __shared__ __align__(16) short smem[67584];
    short* const wst0 = smem;
    short* const wst1 = smem + 12288;
    short* const Qs   = smem;                // alias (written after wst dead)
    short* const Pb   = smem + 24576;
    short* const Ks   = smem + 34816;
    short* const Vt   = smem + 51200;

    const int tid  = threadIdx.x;
    const int b    = blockIdx.x;
    const int w    = tid >> 6;        // 0..15
    const int lane = tid & 63;
    const int g    = lane >> 4;
    const int i    = lane & 15;
    const int wr   = w >> 1;          // 0..7  row band (32 rows)
    const int wc   = w & 1;           // 0..1  col half (96 cols)

    const float* xb = x + (size_t)b * T_ * C_;
    const float* Wm[3] = { Wk, Wq, Wv };

    f32x4 accP[2][6];
    #pragma unroll
    for (int m = 0; m < 2; m++)
        #pragma unroll
        for (int nb = 0; nb < 6; nb++) accP[m][nb] = f32x4{0.f, 0.f, 0.f, 0.f};

    // per-lane global bases for this wave's two A-strips
    const float* xrow0 = xb + (size_t)(32 * wr + i) * C_ + g * 8;
    const float* xrow1 = xrow0 + 16 * C_;

    float4 xrf[2][2][2];   // [m][ks][half] raw fp32 prefetch for next chunk
    float  wf[3][4];       // W staging prefetch (thread stages k-quad w, col lane)

    auto loadX = [&](int kc) {
        #pragma unroll
        for (int ks = 0; ks < 2; ks++)
            #pragma unroll
            for (int h = 0; h < 2; h++) {
                xrf[0][ks][h] = *(const float4*)(xrow0 + kc + ks * 32 + h * 4);
                xrf[1][ks][h] = *(const float4*)(xrow1 + kc + ks * 32 + h * 4);
            }
    };
    auto loadW = [&](int kc) {
        #pragma unroll
        for (int m = 0; m < 3; m++) {
            const float* Wp = Wm[m] + (size_t)(kc + w * 4) * H_ + lane;
            #pragma unroll
            for (int jj = 0; jj < 4; jj++) wf[m][jj] = Wp[jj * H_];
        }
    };
    auto writeW = [&](short* buf) {
        #pragma unroll
        for (int m = 0; m < 3; m++) {
            const int row = m * 64 + lane;
            const int k0  = w * 4;
            bf16x4 pk;
            union { unsigned u; short s[2]; } p0, p1;
            p0.u = cvt_pk_bf16(wf[m][0], wf[m][1]);
            p1.u = cvt_pk_bf16(wf[m][2], wf[m][3]);
            pk[0] = p0.s[0]; pk[1] = p0.s[1]; pk[2] = p1.s[0]; pk[3] = p1.s[1];
            *(bf16x4*)&buf[row * 64 + (((k0 >> 3) ^ (row & 7)) << 3) + (k0 & 7)] = pk;
        }
    };

    // ---------------- Phase 1 ----------------
    loadX(0); loadW(0);
    writeW(wst0);
    asm volatile("s_waitcnt lgkmcnt(0)\n\ts_barrier" ::: "memory");

    #pragma unroll
    for (int j = 0; j < 6; j++) {
        short* const cur = (j & 1) ? wst1 : wst0;
        short* const alt = (j & 1) ? wst0 : wst1;

        // convert prefetched x -> A fragments
        bf16x8 afs[2][2];
        #pragma unroll
        for (int m = 0; m < 2; m++)
            #pragma unroll
            for (int ks = 0; ks < 2; ks++) {
                union { bf16x8 v; unsigned u[4]; } a;
                a.u[0] = cvt_pk_bf16(xrf[m][ks][0].x, xrf[m][ks][0].y);
                a.u[1] = cvt_pk_bf16(xrf[m][ks][0].z, xrf[m][ks][0].w);
                a.u[2] = cvt_pk_bf16(xrf[m][ks][1].x, xrf[m][ks][1].y);
                a.u[3] = cvt_pk_bf16(xrf[m][ks][1].z, xrf[m][ks][1].w);
                afs[m][ks] = a.v;
            }

        if (j < 5) { loadX((j + 1) * 64); loadW((j + 1) * 64); }   // overlap with MFMAs

        #pragma unroll
        for (int nb = 0; nb < 6; nb++) {
            const int brow = 96 * wc + 16 * nb + i;   // (96*wc+16*nb)%8==0 -> brow&7 == i&7
            #pragma unroll
            for (int ks = 0; ks < 2; ks++) {
                const bf16x8 bfr = *(const bf16x8*)&cur[brow * 64 + (((ks * 4 + g) ^ (i & 7)) << 3)];
                accP[0][nb] = __builtin_amdgcn_mfma_f32_16x16x32_bf16(afs[0][ks], bfr, accP[0][nb], 0, 0, 0);
                accP[1][nb] = __builtin_amdgcn_mfma_f32_16x16x32_bf16(afs[1][ks], bfr, accP[1][nb], 0, 0, 0);
            }
        }

        if (j < 5) writeW(alt);   // LDS write late (T14): W global latency hidden by MFMAs
        asm volatile("s_waitcnt lgkmcnt(0)\n\ts_barrier" ::: "memory");
    }

    // ---------------- Epilogue: scatter K,Q (b16) and V (packed b64) ----------------
    #pragma unroll
    for (int m = 0; m < 2; m++) {
        const int row0 = 32 * wr + 16 * m + 4 * g;
        #pragma unroll
        for (int nb = 0; nb < 6; nb++) {
            const int gc = 96 * wc + 16 * nb;   // wave-uniform
            if (gc < 64) {
                #pragma unroll
                for (int r = 0; r < 4; r++)
                    Ks[swz64(row0 + r, gc + i)] = (short)f2bf(accP[m][nb][r]);
            } else if (gc < 128) {
                #pragma unroll
                for (int r = 0; r < 4; r++)
                    Qs[swz64(row0 + r, gc - 64 + i)] = (short)f2bf(accP[m][nb][r]);
            } else {
                const int hrow = gc - 128 + i;
                const int t0   = row0;
                bf16x4 pk;
                #pragma unroll
                for (int r = 0; r < 4; r++) pk[r] = (short)f2bf(accP[m][nb][r]);
                const int blk = t0 >> 3;
                *(bf16x4*)&Vt[hrow * 256 + (((blk & ~7) | ((blk ^ (hrow & 7)) & 7)) << 3) + (t0 & 7)] = pk;
            }
        }
    }
    asm volatile("s_waitcnt lgkmcnt(0)\n\ts_barrier" ::: "memory");

    // ---------------- Phase 2: causal attention (wave w owns rows [16w,16w+16)) ------
    const int rb = 16 * w;
    bf16x8 qf[2];
    #pragma unroll
    for (int ks = 0; ks < 2; ks++)
        qf[ks] = *(const bf16x8*)&Qs[(rb + i) * 64 + (((ks * 4 + g) ^ (i & 7)) << 3)];

    short* myP = Pb + w * 640;                 // [16][40] shorts, block-swizzled
    const float NEG_INF = -__builtin_inff();
    const int lim = w;

    f32x4 accS[16];
    #pragma unroll
    for (int nt = 0; nt < 16; nt++) accS[nt] = f32x4{0.f, 0.f, 0.f, 0.f};

    #pragma unroll
    for (int nt = 0; nt < 16; nt++) {
        if (nt <= lim) {
            #pragma unroll
            for (int ks = 0; ks < 2; ks++) {
                const bf16x8 kf = *(const bf16x8*)&Ks[(nt * 16 + i) * 64 + (((ks * 4 + g) ^ (i & 7)) << 3)];
                accS[nt] = __builtin_amdgcn_mfma_f32_16x16x32_bf16(qf[ks], kf, accS[nt], 0, 0, 0);
            }
        }
    }

    float mrow[4] = { NEG_INF, NEG_INF, NEG_INF, NEG_INF };
    #pragma unroll
    for (int nt = 0; nt < 16; nt++)
        #pragma unroll
        for (int r = 0; r < 4; r++) {
            const int col = nt * 16 + i;
            const int row = rb + 4 * g + r;
            float v = accS[nt][r] * SCALE_;
            v = (col <= row) ? v : NEG_INF;
            accS[nt][r] = v;
            mrow[r] = fmaxf(mrow[r], v);
        }
    #pragma unroll
    for (int r = 0; r < 4; r++)
        #pragma unroll
        for (int msk = 1; msk < 16; msk <<= 1)
            mrow[r] = fmaxf(mrow[r], __shfl_xor(mrow[r], msk, 64));

    float lsum[4] = { 0.f, 0.f, 0.f, 0.f };
    #pragma unroll
    for (int nt = 0; nt < 16; nt++)
        #pragma unroll
        for (int r = 0; r < 4; r++) {
            const float p = __expf(accS[nt][r] - mrow[r]);
            accS[nt][r] = p;
            lsum[r] += p;
        }
    #pragma unroll
    for (int r = 0; r < 4; r++)
        #pragma unroll
        for (int msk = 1; msk < 16; msk <<= 1)
            lsum[r] += __shfl_xor(lsum[r], msk, 64);

    f32x4 accO[4];
    #pragma unroll
    for (int ht = 0; ht < 4; ht++) accO[ht] = f32x4{0.f, 0.f, 0.f, 0.f};

    #pragma unroll
    for (int ck = 0; ck < 8; ck++) {
        if (2 * ck <= lim) {
            #pragma unroll
            for (int t2 = 0; t2 < 2; t2++)
                #pragma unroll
                for (int r = 0; r < 4; r++) {
                    const int q = 4 * g + r, kk = t2 * 16 + i;
                    myP[q * 40 + ((((kk >> 3) ^ (q >> 2)) & 3) << 3) + (kk & 7)] =
                        (short)f2bf(accS[2 * ck + t2][r]);
                }
            asm volatile("s_waitcnt lgkmcnt(0)" ::: "memory");
            const bf16x8 pf = *(const bf16x8*)&myP[i * 40 + (((g ^ (i >> 2)) & 3) << 3)];
            #pragma unroll
            for (int ht = 0; ht < 4; ht++) {
                const int hrow = ht * 16 + i;
                const int blk  = ck * 4 + g;
                const bf16x8 vf = *(const bf16x8*)&Vt[hrow * 256 +
                        (((blk & ~7) | ((blk ^ (hrow & 7)) & 7)) << 3)];
                accO[ht] = __builtin_amdgcn_mfma_f32_16x16x32_bf16(pf, vf, accO[ht], 0, 0, 0);
            }
        }
    }

    float inv[4];
    #pragma unroll
    for (int r = 0; r < 4; r++) inv[r] = 1.f / lsum[r];
    #pragma unroll
    for (int ht = 0; ht < 4; ht++)
        #pragma unroll
        for (int r = 0; r < 4; r++) {
            const int row = rb + 4 * g + r;
            out[((size_t)b * T_ + row) * H_ + ht * 16 + i] = accO[ht][r] * inv[r];
        }
}

extern "C" void kernel_launch(void* const* d_in, const int* in_sizes, int n_in,
                              void* d_out, int out_size, void* d_ws, size_t ws_size,
                              hipStream_t stream) {
    const float* x  = (const float*)d_in[0];
    const float* Wk = (const float*)d_in[1];
    const float* Wq = (const float*)d_in[2];
    const float* Wv = (const float*)d_in[3];
    float* out = (float*)d_out;
    (void)d_ws; (void)ws_size; (void)in_sizes; (void)n_in; (void)out_size;
    att_head_kernel<<<dim3(B_), dim3(1024), 0, stream>>>(x, Wk, Wq, Wv, out);
}